// Round 6
// baseline (205.239 us; speedup 1.0000x reference)
//
#include <hip/hip_runtime.h>

// Problem constants (reference: N=2048, F=128, HEADS=8, OUT_DIM=8, ALPHA=0.2)
#define NN      2048
#define FDIM    128
#define HEADS   8
#define ODIM    8
#define HID     64      // HEADS*ODIM
#define ALPHA   0.2f

__device__ __forceinline__ float lrelu(float x) {
    return x > 0.f ? x : ALPHA * x;
}

// readfirstlane for float: ONLY for values uniform across the whole wave.
// R5 bug: hh depended on (t&1) -> NOT uniform -> rfl broadcast lane 0's
// half to everyone (absmax 1.9e-2). s1/LF remain legal (one row per block).
__device__ __forceinline__ float rfl(float x) {
    return __int_as_float(__builtin_amdgcn_readfirstlane(__float_as_int(x)));
}

// ---------------------------------------------------------------------------
// Kernel 1: h = X @ W  (per-node row), s1 = h . a1, s2 = h . a2  (per head)
// grid = NN blocks, block = 64 threads (1 wave)
// ---------------------------------------------------------------------------
__global__ __launch_bounds__(64) void gat_prep(
        const float* __restrict__ X,   // (NN, FDIM)
        const float* __restrict__ W,   // (FDIM, HID)
        const float* __restrict__ ak,  // (2*ODIM,)
        float* __restrict__ H,         // (NN, HID)
        float* __restrict__ S1,        // (NN, HEADS)
        float* __restrict__ S2) {      // (NN, HEADS)
    const int n = blockIdx.x;
    const int t = threadIdx.x;

    __shared__ float Xs[FDIM];
    __shared__ float hs[HID];

    Xs[t]      = X[(size_t)n * FDIM + t];
    Xs[t + 64] = X[(size_t)n * FDIM + 64 + t];
    __syncthreads();

    float acc = 0.f;
    #pragma unroll 8
    for (int k = 0; k < FDIM; ++k)
        acc = fmaf(Xs[k], W[k * HID + t], acc);   // Xs[k]: LDS broadcast; W col: coalesced

    H[(size_t)n * HID + t] = acc;
    hs[t] = acc;
    __syncthreads();

    if (t < 16) {
        const int head = t & 7;
        const float* a = ak + ((t < 8) ? 0 : ODIM);
        float s = 0.f;
        #pragma unroll
        for (int d = 0; d < ODIM; ++d)
            s = fmaf(hs[head * ODIM + d], a[d], s);
        if (t < 8) S1[n * HEADS + head] = s;
        else       S2[n * HEADS + head] = s;
    }
}

// ---------------------------------------------------------------------------
// Kernel 2: softmax denominators only.
// LF[i,h] = sum_j (A[i,j]>0) * exp(lrelu(s1[i,h]+s2[j,h]))
// Max-free: scores O(1); masked lanes contribute exactly 0 (matches
// reference exp(-1e9)==0 in fp32). grid = NN, block = 512, 4 j/thread.
// ---------------------------------------------------------------------------
__global__ __launch_bounds__(512) void gat_rowsum(
        const int*   __restrict__ A,    // (NN, NN)
        const float* __restrict__ S1,   // (NN, HEADS)
        const float* __restrict__ S2,   // (NN, HEADS)
        float* __restrict__ LF) {       // (NN, HEADS)
    const int i    = blockIdx.x;
    const int t    = threadIdx.x;
    const int wave = t >> 6;
    const int lane = t & 63;

    __shared__ float redL[8 * HEADS];

    float s1r[HEADS];
    #pragma unroll
    for (int h = 0; h < HEADS; ++h)
        s1r[h] = rfl(S1[i * HEADS + h]);   // row-uniform: legal

    float ls[HEADS];
    #pragma unroll
    for (int h = 0; h < HEADS; ++h) ls[h] = 0.f;

    #pragma unroll
    for (int jj = 0; jj < 4; ++jj) {
        const int j = t + jj * 512;               // coalesced
        const bool msk = A[(size_t)i * NN + j] > 0;
        const float4 sa = *(const float4*)(S2 + j * HEADS);
        const float4 sb = *(const float4*)(S2 + j * HEADS + 4);
        const float s2v[8] = {sa.x, sa.y, sa.z, sa.w,
                              sb.x, sb.y, sb.z, sb.w};
        #pragma unroll
        for (int h = 0; h < HEADS; ++h) {
            const float x = s1r[h] + s2v[h];
            ls[h] += msk ? __expf(lrelu(x)) : 0.f;
        }
    }

    #pragma unroll
    for (int h = 0; h < HEADS; ++h) {
        float v = ls[h];
        #pragma unroll
        for (int off = 32; off; off >>= 1)
            v += __shfl_xor(v, off);
        if (lane == 0) redL[wave * HEADS + h] = v;
    }
    __syncthreads();

    if (t < HEADS) {
        float v = 0.f;
        #pragma unroll
        for (int w = 0; w < 8; ++w)
            v += redL[w * HEADS + t];
        LF[i * HEADS + t] = v;
    }
}

// ---------------------------------------------------------------------------
// Kernel 3: barrier-free dense write stream.
// grid = NN*8 blocks (8 chunks of 256 j per row), block = 512.
// Thread t: j = chunk*256 + t/2, half = t&1 → computes o[d0..d0+3] and
// writes ONE float4 at byte offset 16*t of the block's output span —
// every store instruction covers a dense 1 KB line (ideal sectors).
// s1/1/LF are row-uniform → SGPRs via rfl. H-half is LANE-DEPENDENT (d0)
// → loaded per-lane as float4 (R5's rfl-on-nonuniform bug, fixed).
// NO LDS, NO barriers: stores issue continuously, occupancy is wave-capped.
// ---------------------------------------------------------------------------
__global__ __launch_bounds__(512) void gat_write(
        const int*   __restrict__ A,    // (NN, NN)
        const float* __restrict__ H,    // (NN, HID)
        const float* __restrict__ S1,   // (NN, HEADS)
        const float* __restrict__ S2,   // (NN, HEADS)
        const float* __restrict__ LF,   // (NN, HEADS)
        float* __restrict__ out) {      // (NN, NN, ODIM)
    const int bid   = blockIdx.x;
    const int i     = bid >> 3;          // row
    const int chunk = bid & 7;           // 256-j chunk within row
    const int t     = threadIdx.x;
    const int j     = chunk * 256 + (t >> 1);
    const int d0    = (t & 1) * 4;       // which half of the 8 outputs

    // row-uniform scalars (legal rfl) + per-lane H half (VGPRs)
    float s1r[HEADS], hh[HEADS][4];
    #pragma unroll
    for (int h = 0; h < HEADS; ++h) {
        s1r[h] = rfl(S1[i * HEADS + h]);
        const float inv = rfl(1.0f / LF[i * HEADS + h]);
        const float4 hv = *(const float4*)(H + (size_t)i * HID + h * ODIM + d0);
        hh[h][0] = hv.x * inv;
        hh[h][1] = hv.y * inv;
        hh[h][2] = hv.z * inv;
        hh[h][3] = hv.w * inv;
    }

    const bool msk = A[(size_t)i * NN + j] > 0;
    const float4 sa = *(const float4*)(S2 + j * HEADS);
    const float4 sb = *(const float4*)(S2 + j * HEADS + 4);
    const float s2v[8] = {sa.x, sa.y, sa.z, sa.w,
                          sb.x, sb.y, sb.z, sb.w};

    float p[HEADS];
    #pragma unroll
    for (int h = 0; h < HEADS; ++h) {
        const float x = s1r[h] + s2v[h];
        p[h] = msk ? __expf(lrelu(x)) : 0.f;
    }

    float o[4];
    #pragma unroll
    for (int d = 0; d < 4; ++d) o[d] = 0.f;
    #pragma unroll
    for (int h = 0; h < HEADS; ++h) {
        #pragma unroll
        for (int d = 0; d < 4; ++d)
            o[d] = fmaf(p[h], hh[h][d], o[d]);
    }

    float4 ov;
    ov.x = lrelu(o[0]); ov.y = lrelu(o[1]);
    ov.z = lrelu(o[2]); ov.w = lrelu(o[3]);
    *(float4*)(out + ((size_t)i * NN + j) * ODIM + d0) = ov;  // dense 16B/lane
}

// ---------------------------------------------------------------------------
extern "C" void kernel_launch(void* const* d_in, const int* in_sizes, int n_in,
                              void* d_out, int out_size, void* d_ws, size_t ws_size,
                              hipStream_t stream) {
    const float* X  = (const float*)d_in[0];   // (2048,128) fp32
    const int*   A  = (const int*)  d_in[1];   // (2048,2048) int32
    const float* W  = (const float*)d_in[2];   // (128,64) fp32
    const float* ak = (const float*)d_in[3];   // (16,1) fp32
    float* out = (float*)d_out;                // (2048*2048*8) fp32

    // workspace layout: H (512 KB) | S1 (64 KB) | S2 (64 KB) | LF (64 KB)
    float* H  = (float*)d_ws;
    float* S1 = H  + (size_t)NN * HID;
    float* S2 = S1 + (size_t)NN * HEADS;
    float* LF = S2 + (size_t)NN * HEADS;

    gat_prep  <<<NN,      64, 0, stream>>>(X, W, ak, H, S1, S2);
    gat_rowsum<<<NN,     512, 0, stream>>>(A, S1, S2, LF);
    gat_write <<<NN * 8, 512, 0, stream>>>(A, H, S1, S2, LF, out);
}

// Round 7
// 190.899 us; speedup vs baseline: 1.0751x; 1.0751x over previous
//
#include <hip/hip_runtime.h>

// Problem constants (reference: N=2048, F=128, HEADS=8, OUT_DIM=8, ALPHA=0.2)
#define NN      2048
#define FDIM    128
#define HEADS   8
#define ODIM    8
#define HID     64      // HEADS*ODIM
#define ALPHA   0.2f

__device__ __forceinline__ float lrelu(float x) {
    return x > 0.f ? x : ALPHA * x;
}

// readfirstlane for float: ONLY legal for wave-uniform values.
// Here each block = ONE wave = ONE row i, so all row data (s1, LF, H*inv)
// is wave-uniform by construction. (R5 bug: rfl of a lane-dependent value.)
__device__ __forceinline__ float rfl(float x) {
    return __int_as_float(__builtin_amdgcn_readfirstlane(__float_as_int(x)));
}

// ---------------------------------------------------------------------------
// Kernel 1: h = X @ W  (per-node row), s1 = h . a1, s2 = h . a2  (per head)
// grid = NN blocks, block = 64 threads (1 wave)
// ---------------------------------------------------------------------------
__global__ __launch_bounds__(64) void gat_prep(
        const float* __restrict__ X,   // (NN, FDIM)
        const float* __restrict__ W,   // (FDIM, HID)
        const float* __restrict__ ak,  // (2*ODIM,)
        float* __restrict__ H,         // (NN, HID)
        float* __restrict__ S1,        // (NN, HEADS)
        float* __restrict__ S2) {      // (NN, HEADS)
    const int n = blockIdx.x;
    const int t = threadIdx.x;

    __shared__ float Xs[FDIM];
    __shared__ float hs[HID];

    Xs[t]      = X[(size_t)n * FDIM + t];
    Xs[t + 64] = X[(size_t)n * FDIM + 64 + t];
    __syncthreads();

    float acc = 0.f;
    #pragma unroll 8
    for (int k = 0; k < FDIM; ++k)
        acc = fmaf(Xs[k], W[k * HID + t], acc);   // Xs[k]: LDS broadcast; W col: coalesced

    H[(size_t)n * HID + t] = acc;
    hs[t] = acc;
    __syncthreads();

    if (t < 16) {
        const int head = t & 7;
        const float* a = ak + ((t < 8) ? 0 : ODIM);
        float s = 0.f;
        #pragma unroll
        for (int d = 0; d < ODIM; ++d)
            s = fmaf(hs[head * ODIM + d], a[d], s);
        if (t < 8) S1[n * HEADS + head] = s;
        else       S2[n * HEADS + head] = s;
    }
}

// ---------------------------------------------------------------------------
// Kernel 2 (R7): ONE WAVE PER ROW. grid = NN blocks x 64 threads.
// Zero LDS, zero barriers. Lane L owns j = L + jj*64, jj < 32.
//   pass A: accumulate ls[h] = sum over owned j of mask*exp(lrelu(s1+s2));
//           A-mask packed into one 32-bit reg (A read ONCE);
//           LF via 6-step __shfl_xor butterfly (wave64 lockstep, no sync).
//   pass B: recompute p (exp is ~2 cyc/lane amortized), o = p . (H/LF),
//           two dense float4 stores per j (32-B lane stride, full sectors,
//           the R4-verified layout). Stores issue CONTINUOUSLY — no
//           barrier-gated tail burst (the R3-profile bottleneck: occ 42%,
//           VALUBusy 23%, 2.2 TB/s from store clustering).
// Row constants amortized over 32 j: s1, inv=1/LF, hh=H*inv all in SGPRs
// via rfl (wave-uniform: one row per wave). v_fma takes 1 SGPR operand.
// ---------------------------------------------------------------------------
__global__ __launch_bounds__(64) void gat_row(
        const int*   __restrict__ A,    // (NN, NN)
        const float* __restrict__ H,    // (NN, HID)
        const float* __restrict__ S1,   // (NN, HEADS)
        const float* __restrict__ S2,   // (NN, HEADS)
        float* __restrict__ out) {      // (NN, NN, ODIM)
    const int i    = blockIdx.x;
    const int lane = threadIdx.x;

    // s1: wave-uniform -> SGPR
    float s1r[HEADS];
    #pragma unroll
    for (int h = 0; h < HEADS; ++h)
        s1r[h] = rfl(S1[i * HEADS + h]);

    // ---- pass A: denominators + A-bitmask ------------------------------
    unsigned int mbits = 0u;
    float ls[HEADS];
    #pragma unroll
    for (int h = 0; h < HEADS; ++h) ls[h] = 0.f;

    #pragma unroll 8
    for (int jj = 0; jj < 32; ++jj) {
        const int j = lane + jj * 64;             // coalesced dword
        const bool msk = A[(size_t)i * NN + j] > 0;
        mbits |= (msk ? 1u : 0u) << jj;
        const float4 sa = *(const float4*)(S2 + j * HEADS);
        const float4 sb = *(const float4*)(S2 + j * HEADS + 4);
        const float s2v[8] = {sa.x, sa.y, sa.z, sa.w,
                              sb.x, sb.y, sb.z, sb.w};
        #pragma unroll
        for (int h = 0; h < HEADS; ++h) {
            const float x = s1r[h] + s2v[h];
            ls[h] += msk ? __expf(lrelu(x)) : 0.f;
        }
    }

    // in-wave butterfly: every lane ends with the full row sum per head
    #pragma unroll
    for (int h = 0; h < HEADS; ++h) {
        float v = ls[h];
        #pragma unroll
        for (int off = 32; off; off >>= 1)
            v += __shfl_xor(v, off);
        ls[h] = v;                                 // wave-uniform now
    }

    // hh = H_row * (1/LF): wave-uniform -> SGPRs (mul in VALU, then rfl)
    float inv_s[HEADS];
    #pragma unroll
    for (int h = 0; h < HEADS; ++h)
        inv_s[h] = rfl(1.0f / ls[h]);

    float hh_s[HID];
    #pragma unroll
    for (int k = 0; k < 16; ++k) {
        const float4 hv = *(const float4*)(H + (size_t)i * HID + k * 4);
        const float iv  = inv_s[k >> 1];           // k*4/8 = k/2 = head
        hh_s[k * 4 + 0] = rfl(hv.x * iv);
        hh_s[k * 4 + 1] = rfl(hv.y * iv);
        hh_s[k * 4 + 2] = rfl(hv.z * iv);
        hh_s[k * 4 + 3] = rfl(hv.w * iv);
    }

    // ---- pass B: recompute p, accumulate, stream stores ----------------
    #pragma unroll 8
    for (int jj = 0; jj < 32; ++jj) {
        const int j = lane + jj * 64;
        const bool msk = (mbits >> jj) & 1u;       // no A re-read
        const float4 sa = *(const float4*)(S2 + j * HEADS);   // L2 hit
        const float4 sb = *(const float4*)(S2 + j * HEADS + 4);
        const float s2v[8] = {sa.x, sa.y, sa.z, sa.w,
                              sb.x, sb.y, sb.z, sb.w};

        float p[HEADS];
        #pragma unroll
        for (int h = 0; h < HEADS; ++h) {
            const float x = s1r[h] + s2v[h];
            p[h] = msk ? __expf(lrelu(x)) : 0.f;
        }

        float o[ODIM];
        #pragma unroll
        for (int d = 0; d < ODIM; ++d) o[d] = 0.f;
        #pragma unroll
        for (int h = 0; h < HEADS; ++h) {
            #pragma unroll
            for (int d = 0; d < ODIM; ++d)
                o[d] = fmaf(p[h], hh_s[h * ODIM + d], o[d]);  // SGPR operand
        }

        const size_t base = ((size_t)i * NN + j) * ODIM;
        float4 o0, o1;
        o0.x = lrelu(o[0]); o0.y = lrelu(o[1]);
        o0.z = lrelu(o[2]); o0.w = lrelu(o[3]);
        o1.x = lrelu(o[4]); o1.y = lrelu(o[5]);
        o1.z = lrelu(o[6]); o1.w = lrelu(o[7]);
        *(float4*)(out + base)     = o0;   // 32-B lane stride, dense sectors
        *(float4*)(out + base + 4) = o1;
    }
}

// ---------------------------------------------------------------------------
extern "C" void kernel_launch(void* const* d_in, const int* in_sizes, int n_in,
                              void* d_out, int out_size, void* d_ws, size_t ws_size,
                              hipStream_t stream) {
    const float* X  = (const float*)d_in[0];   // (2048,128) fp32
    const int*   A  = (const int*)  d_in[1];   // (2048,2048) int32
    const float* W  = (const float*)d_in[2];   // (128,64) fp32
    const float* ak = (const float*)d_in[3];   // (16,1) fp32
    float* out = (float*)d_out;                // (2048*2048*8) fp32

    // workspace layout: H (512 KB) | S1 (64 KB) | S2 (64 KB)
    float* H  = (float*)d_ws;
    float* S1 = H  + (size_t)NN * HID;
    float* S2 = S1 + (size_t)NN * HEADS;

    gat_prep<<<NN, 64, 0, stream>>>(X, W, ak, H, S1, S2);
    gat_row <<<NN, 64, 0, stream>>>(A, H, S1, S2, out);
}

// Round 9
// 190.414 us; speedup vs baseline: 1.0779x; 1.0025x over previous
//
#include <hip/hip_runtime.h>

// Problem constants (reference: N=2048, F=128, HEADS=8, OUT_DIM=8, ALPHA=0.2)
#define NN      2048
#define FDIM    128
#define HEADS   8
#define ODIM    8
#define HID     64      // HEADS*ODIM
#define ALPHA   0.2f

// native clang vectors: __builtin_nontemporal_* requires real vector types,
// not HIP's HIP_vector_type classes (R8 compile failure).
typedef float fx4 __attribute__((ext_vector_type(4)));
typedef int   ix4 __attribute__((ext_vector_type(4)));

__device__ __forceinline__ float lrelu(float x) {
    return x > 0.f ? x : ALPHA * x;
}

// readfirstlane: ONLY for wave-uniform values. Each block serves ONE row i,
// so row data (s1, LF, H*inv) is uniform across every wave in the block.
__device__ __forceinline__ float rfl(float x) {
    return __int_as_float(__builtin_amdgcn_readfirstlane(__float_as_int(x)));
}

// ---------------------------------------------------------------------------
// Kernel 1: h = X @ W  (per-node row), s1 = h . a1, s2 = h . a2  (per head)
// grid = NN blocks, block = 64 threads (1 wave)
// ---------------------------------------------------------------------------
__global__ __launch_bounds__(64) void gat_prep(
        const float* __restrict__ X,   // (NN, FDIM)
        const float* __restrict__ W,   // (FDIM, HID)
        const float* __restrict__ ak,  // (2*ODIM,)
        float* __restrict__ H,         // (NN, HID)
        float* __restrict__ S1,        // (NN, HEADS)
        float* __restrict__ S2) {      // (NN, HEADS)
    const int n = blockIdx.x;
    const int t = threadIdx.x;

    __shared__ float Xs[FDIM];
    __shared__ float hs[HID];

    Xs[t]      = X[(size_t)n * FDIM + t];
    Xs[t + 64] = X[(size_t)n * FDIM + 64 + t];
    __syncthreads();

    float acc = 0.f;
    #pragma unroll 8
    for (int k = 0; k < FDIM; ++k)
        acc = fmaf(Xs[k], W[k * HID + t], acc);   // Xs[k]: LDS broadcast; W col: coalesced

    H[(size_t)n * HID + t] = acc;
    hs[t] = acc;
    __syncthreads();

    if (t < 16) {
        const int head = t & 7;
        const float* a = ak + ((t < 8) ? 0 : ODIM);
        float s = 0.f;
        #pragma unroll
        for (int d = 0; d < ODIM; ++d)
            s = fmaf(hs[head * ODIM + d], a[d], s);
        if (t < 8) S1[n * HEADS + head] = s;
        else       S2[n * HEADS + head] = s;
    }
}

// ---------------------------------------------------------------------------
// Kernel 2 (fused; R9 = R8 retry with ext_vector_type for NT builtins):
//   - A row staged to LDS via NONTEMPORAL ix4 loads (read-once data)
//   - output stored via NONTEMPORAL fx4 (write-once 134 MB stream was
//     sweeping L2 between pass A and B — R3 capture: 2.2 TB/s, VALU 23%)
//   - s1 / hh=H/LF in scalar regs via rfl (R3-verified: no spill)
//   - pass-A mask bits kept in a register; pass B never re-reads As
// grid = NN blocks, block = 256 (4 waves), 8 j per thread,
// stores at 32-B lane stride (R4-verified full-sector layout).
// ---------------------------------------------------------------------------
__global__ __launch_bounds__(256) void gat_fused(
        const int*   __restrict__ A,    // (NN, NN)
        const float* __restrict__ H,    // (NN, HID)
        const float* __restrict__ S1,   // (NN, HEADS)
        const float* __restrict__ S2,   // (NN, HEADS)
        float* __restrict__ out) {      // (NN, NN, ODIM)
    const int i    = blockIdx.x;
    const int t    = threadIdx.x;
    const int wave = t >> 6;
    const int lane = t & 63;

    __shared__ int   As[NN];            // 8 KB adjacency row
    __shared__ float redL[4 * HEADS];
    __shared__ float LFs[HEADS];

    // nontemporal staging: A row used once per kernel
    {
        const ix4* Arow4 = (const ix4*)(A + (size_t)i * NN);
        ((ix4*)As)[t]       = __builtin_nontemporal_load(Arow4 + t);
        ((ix4*)As)[t + 256] = __builtin_nontemporal_load(Arow4 + t + 256);
    }

    // s1: row-uniform -> scalar regs
    float s1r[HEADS];
    #pragma unroll
    for (int h = 0; h < HEADS; ++h)
        s1r[h] = rfl(S1[i * HEADS + h]);

    __syncthreads();

    // ---- pass A: softmax denominators + mask bits ----------------------
    unsigned int mbits = 0u;
    float ls[HEADS];
    #pragma unroll
    for (int h = 0; h < HEADS; ++h) ls[h] = 0.f;

    #pragma unroll
    for (int jj = 0; jj < 8; ++jj) {
        const int j = t + jj * 256;               // contiguous lane mapping
        const bool msk = As[j] > 0;
        mbits |= (msk ? 1u : 0u) << jj;
        const fx4 sa = *(const fx4*)(S2 + j * HEADS);
        const fx4 sb = *(const fx4*)(S2 + j * HEADS + 4);
        const float s2v[8] = {sa.x, sa.y, sa.z, sa.w,
                              sb.x, sb.y, sb.z, sb.w};
        #pragma unroll
        for (int h = 0; h < HEADS; ++h) {
            const float x = s1r[h] + s2v[h];
            ls[h] += msk ? __expf(lrelu(x)) : 0.f;
        }
    }

    // wave butterfly + cross-wave reduce → LFs[h]
    #pragma unroll
    for (int h = 0; h < HEADS; ++h) {
        float v = ls[h];
        #pragma unroll
        for (int off = 32; off; off >>= 1)
            v += __shfl_xor(v, off);
        if (lane == 0) redL[wave * HEADS + h] = v;
    }
    __syncthreads();

    if (t < HEADS) {
        float v = 0.f;
        #pragma unroll
        for (int w = 0; w < 4; ++w)
            v += redL[w * HEADS + t];
        LFs[t] = v;
    }
    __syncthreads();

    // hh = H_row / LF: row-uniform -> scalar regs (R3-verified, no spill)
    float hh_s[HID];
    #pragma unroll
    for (int k = 0; k < 16; ++k) {
        const fx4 hv = *(const fx4*)(H + (size_t)i * HID + k * 4);
        const float iv  = 1.0f / LFs[k >> 1];      // head = (k*4)/8
        hh_s[k * 4 + 0] = rfl(hv.x * iv);
        hh_s[k * 4 + 1] = rfl(hv.y * iv);
        hh_s[k * 4 + 2] = rfl(hv.z * iv);
        hh_s[k * 4 + 3] = rfl(hv.w * iv);
    }

    // ---- pass B: recompute p (S2 is L2-warm), FMA, NT-stream out -------
    #pragma unroll
    for (int jj = 0; jj < 8; ++jj) {
        const int j = t + jj * 256;
        const bool msk = (mbits >> jj) & 1u;       // no As re-read
        const fx4 sa = *(const fx4*)(S2 + j * HEADS);
        const fx4 sb = *(const fx4*)(S2 + j * HEADS + 4);
        const float s2v[8] = {sa.x, sa.y, sa.z, sa.w,
                              sb.x, sb.y, sb.z, sb.w};

        float p[HEADS];
        #pragma unroll
        for (int h = 0; h < HEADS; ++h) {
            const float x = s1r[h] + s2v[h];
            p[h] = msk ? __expf(lrelu(x)) : 0.f;
        }

        float o[ODIM];
        #pragma unroll
        for (int d = 0; d < ODIM; ++d) o[d] = 0.f;
        #pragma unroll
        for (int h = 0; h < HEADS; ++h) {
            #pragma unroll
            for (int d = 0; d < ODIM; ++d)
                o[d] = fmaf(p[h], hh_s[h * ODIM + d], o[d]);  // scalar operand
        }

        const size_t base = ((size_t)i * NN + j) * ODIM;
        fx4 o0, o1;
        o0.x = lrelu(o[0]); o0.y = lrelu(o[1]);
        o0.z = lrelu(o[2]); o0.w = lrelu(o[3]);
        o1.x = lrelu(o[4]); o1.y = lrelu(o[5]);
        o1.z = lrelu(o[6]); o1.w = lrelu(o[7]);
        // write-once stream: bypass cache, keep L2 for S2
        __builtin_nontemporal_store(o0, (fx4*)(out + base));
        __builtin_nontemporal_store(o1, (fx4*)(out + base + 4));
    }
}

// ---------------------------------------------------------------------------
extern "C" void kernel_launch(void* const* d_in, const int* in_sizes, int n_in,
                              void* d_out, int out_size, void* d_ws, size_t ws_size,
                              hipStream_t stream) {
    const float* X  = (const float*)d_in[0];   // (2048,128) fp32
    const int*   A  = (const int*)  d_in[1];   // (2048,2048) int32
    const float* W  = (const float*)d_in[2];   // (128,64) fp32
    const float* ak = (const float*)d_in[3];   // (16,1) fp32
    float* out = (float*)d_out;                // (2048*2048*8) fp32

    // workspace layout: H (512 KB) | S1 (64 KB) | S2 (64 KB)
    float* H  = (float*)d_ws;
    float* S1 = H  + (size_t)NN * HID;
    float* S2 = S1 + (size_t)NN * HEADS;

    gat_prep <<<NN,  64, 0, stream>>>(X, W, ak, H, S1, S2);
    gat_fused<<<NN, 256, 0, stream>>>(A, H, S1, S2, out);
}

// Round 10
// 175.755 us; speedup vs baseline: 1.1678x; 1.0834x over previous
//
#include <hip/hip_runtime.h>

// Problem constants (reference: N=2048, F=128, HEADS=8, OUT_DIM=8, ALPHA=0.2)
#define NN      2048
#define FDIM    128
#define HEADS   8
#define ODIM    8
#define HID     64      // HEADS*ODIM
#define ALPHA   0.2f

// ---------------------------------------------------------------------------
// R10 = exact restoration of the R2 champion (175.5 us, best of 10 rounds).
// Why this exact configuration (each alternative was MEASURED and lost):
//   - fused 2-pass, 256 thr, launch_bounds(256,2): (256,4) spilled hh to
//     scratch (R1: VGPR=64 reported, 155 us); (256,2) keeps hh[64] in VGPRs.
//   - hh in VGPRs, NOT SGPRs-via-readfirstlane: rfl prologue variants
//     regressed (R4 185.4, R9 190.4 vs this 175.5).
//   - plain float4 stores, NOT nontemporal: NT bypasses L2 write-combining
//     of the 32-B lane-stride store pair -> R9 regressed +15 us.
//   - contiguous lane->j mapping (j = t + jj*256): 4j-per-thread strided
//     layout inflated WRITE_SIZE 1.48x (R3: 198 MB, 218.7 us).
//   - one-wave-per-row (no barriers, max ILP) also lost (R7: 190.9) —
//     2048 waves is too little TLP to hide L2 latency.
// ---------------------------------------------------------------------------

__device__ __forceinline__ float lrelu(float x) {
    return x > 0.f ? x : ALPHA * x;
}

// ---------------------------------------------------------------------------
// Kernel 1: h = X @ W  (per-node row), s1 = h . a1, s2 = h . a2  (per head)
// grid = NN blocks, block = 64 threads (1 wave)
// ---------------------------------------------------------------------------
__global__ __launch_bounds__(64) void gat_prep(
        const float* __restrict__ X,   // (NN, FDIM)
        const float* __restrict__ W,   // (FDIM, HID)
        const float* __restrict__ ak,  // (2*ODIM,)
        float* __restrict__ H,         // (NN, HID)
        float* __restrict__ S1,        // (NN, HEADS)
        float* __restrict__ S2) {      // (NN, HEADS)
    const int n = blockIdx.x;
    const int t = threadIdx.x;

    __shared__ float Xs[FDIM];
    __shared__ float hs[HID];

    Xs[t]      = X[(size_t)n * FDIM + t];
    Xs[t + 64] = X[(size_t)n * FDIM + 64 + t];
    __syncthreads();

    float acc = 0.f;
    #pragma unroll 8
    for (int k = 0; k < FDIM; ++k)
        acc = fmaf(Xs[k], W[k * HID + t], acc);   // Xs[k]: LDS broadcast; W col: coalesced

    H[(size_t)n * HID + t] = acc;
    hs[t] = acc;
    __syncthreads();

    if (t < 16) {
        const int head = t & 7;
        const float* a = ak + ((t < 8) ? 0 : ODIM);
        float s = 0.f;
        #pragma unroll
        for (int d = 0; d < ODIM; ++d)
            s = fmaf(hs[head * ODIM + d], a[d], s);
        if (t < 8) S1[n * HEADS + head] = s;
        else       S2[n * HEADS + head] = s;
    }
}

// ---------------------------------------------------------------------------
// Kernel 2 (FUSED rowsum + write): per row i —
//   pass A: LF[h] = sum_j mask(i,j) * exp(lrelu(s1[i,h]+s2[j,h]))  (block reduce)
//   pass B: out[i,j,d] = lrelu( sum_h p[j,h] * h[i,h,d] / LF[h] )
// Max-free softmax: scores are O(1); masked lanes contribute exactly 0,
// matching reference's exp(-1e9) == 0 in fp32.
// grid = NN blocks, block = 256 (4 waves), 8 j per thread
// ---------------------------------------------------------------------------
__global__ __launch_bounds__(256, 2) void gat_fused(
        const int*   __restrict__ A,    // (NN, NN)
        const float* __restrict__ H,    // (NN, HID)
        const float* __restrict__ S1,   // (NN, HEADS)
        const float* __restrict__ S2,   // (NN, HEADS)
        float* __restrict__ out) {      // (NN, NN, ODIM)
    const int i    = blockIdx.x;
    const int t    = threadIdx.x;
    const int wave = t >> 6;
    const int lane = t & 63;

    __shared__ int   As[NN];            // 8 KB adjacency row
    __shared__ float hhS[HID];          // raw H row (divide happens later)
    __shared__ float redL[4 * HEADS];   // per-wave partial denominators
    __shared__ float LFs[HEADS];        // final denominators

    const int4* Arow4 = (const int4*)(A + (size_t)i * NN);
    ((int4*)As)[t]       = Arow4[t];
    ((int4*)As)[t + 256] = Arow4[t + 256];

    if (t < HID)
        hhS[t] = H[(size_t)i * HID + t];

    float s1r[HEADS];
    #pragma unroll
    for (int h = 0; h < HEADS; ++h) s1r[h] = S1[i * HEADS + h];

    __syncthreads();

    // ---- pass A: softmax denominators ---------------------------------
    float ls[HEADS];
    #pragma unroll
    for (int h = 0; h < HEADS; ++h) ls[h] = 0.f;

    #pragma unroll 2
    for (int jj = 0; jj < 8; ++jj) {
        const int j = t + jj * 256;
        const float4 s2a = *(const float4*)(S2 + j * HEADS);
        const float4 s2b = *(const float4*)(S2 + j * HEADS + 4);
        const bool msk = As[j] > 0;
        const float s2v[8] = {s2a.x, s2a.y, s2a.z, s2a.w,
                              s2b.x, s2b.y, s2b.z, s2b.w};
        #pragma unroll
        for (int h = 0; h < HEADS; ++h) {
            const float x = s1r[h] + s2v[h];
            ls[h] += msk ? __expf(lrelu(x)) : 0.f;
        }
    }

    #pragma unroll
    for (int h = 0; h < HEADS; ++h) {
        float v = ls[h];
        #pragma unroll
        for (int off = 32; off; off >>= 1)
            v += __shfl_xor(v, off);
        if (lane == 0) redL[wave * HEADS + h] = v;
    }
    __syncthreads();

    if (t < HEADS) {
        float v = 0.f;
        #pragma unroll
        for (int w = 0; w < 4; ++w)
            v += redL[w * HEADS + t];
        LFs[t] = v;
    }
    __syncthreads();

    // ---- pass B: recompute p, scale by hh/LF, stream output ------------
    // hh pre-divided into REGISTERS (all indices compile-time constant);
    // hot loop is reg-only except the As broadcast read + s2 L2-hit loads.
    float hh[HID];
    #pragma unroll
    for (int h = 0; h < HEADS; ++h) {
        const float inv = 1.0f / LFs[h];
        const float4 va = *(const float4*)(hhS + h * ODIM);
        const float4 vb = *(const float4*)(hhS + h * ODIM + 4);
        hh[h * ODIM + 0] = va.x * inv;
        hh[h * ODIM + 1] = va.y * inv;
        hh[h * ODIM + 2] = va.z * inv;
        hh[h * ODIM + 3] = va.w * inv;
        hh[h * ODIM + 4] = vb.x * inv;
        hh[h * ODIM + 5] = vb.y * inv;
        hh[h * ODIM + 6] = vb.z * inv;
        hh[h * ODIM + 7] = vb.w * inv;
    }

    #pragma unroll 2
    for (int jj = 0; jj < 8; ++jj) {
        const int j = t + jj * 256;
        const float4 s2a = *(const float4*)(S2 + j * HEADS);
        const float4 s2b = *(const float4*)(S2 + j * HEADS + 4);
        const bool msk = As[j] > 0;
        const float s2v[8] = {s2a.x, s2a.y, s2a.z, s2a.w,
                              s2b.x, s2b.y, s2b.z, s2b.w};

        float p[HEADS];
        #pragma unroll
        for (int h = 0; h < HEADS; ++h) {
            const float x = s1r[h] + s2v[h];
            p[h] = msk ? __expf(lrelu(x)) : 0.f;
        }

        float o[ODIM];
        #pragma unroll
        for (int d = 0; d < ODIM; ++d) o[d] = 0.f;
        #pragma unroll
        for (int h = 0; h < HEADS; ++h) {
            #pragma unroll
            for (int d = 0; d < ODIM; ++d)
                o[d] = fmaf(p[h], hh[h * ODIM + d], o[d]);
        }

        const size_t base = ((size_t)i * NN + j) * ODIM;
        float4 o0, o1;
        o0.x = lrelu(o[0]); o0.y = lrelu(o[1]);
        o0.z = lrelu(o[2]); o0.w = lrelu(o[3]);
        o1.x = lrelu(o[4]); o1.y = lrelu(o[5]);
        o1.z = lrelu(o[6]); o1.w = lrelu(o[7]);
        *(float4*)(out + base)     = o0;   // coalesced 32 B/lane contiguous
        *(float4*)(out + base + 4) = o1;
    }
}

// ---------------------------------------------------------------------------
extern "C" void kernel_launch(void* const* d_in, const int* in_sizes, int n_in,
                              void* d_out, int out_size, void* d_ws, size_t ws_size,
                              hipStream_t stream) {
    const float* X  = (const float*)d_in[0];   // (2048,128) fp32
    const int*   A  = (const int*)  d_in[1];   // (2048,2048) int32
    const float* W  = (const float*)d_in[2];   // (128,64) fp32
    const float* ak = (const float*)d_in[3];   // (16,1) fp32
    float* out = (float*)d_out;                // (2048*2048*8) fp32

    // workspace layout: H (512 KB) | S1 (64 KB) | S2 (64 KB)
    float* H  = (float*)d_ws;
    float* S1 = H  + (size_t)NN * HID;
    float* S2 = S1 + (size_t)NN * HEADS;

    gat_prep <<<NN,  64, 0, stream>>>(X, W, ak, H, S1, S2);
    gat_fused<<<NN, 256, 0, stream>>>(A, H, S1, S2, out);
}